// Round 1
// baseline (33.314 us; speedup 1.0000x reference)
//
#include <hip/hip_runtime.h>

#define SEQ 2048
#define DM  2048
// B = 2, output = broadcast over q of ((sum_s x[b,s,:]) @ wv^T) @ wo^T

// ---- K1a: partial column sums of x: P[(b*16+y)][c] = sum over 128 rows ----
__global__ __launch_bounds__(256)
void colsum_part(const float* __restrict__ x, float* __restrict__ P) {
    int c = blockIdx.x * blockDim.x + threadIdx.x;   // 0..2047
    int y = blockIdx.y;                              // 0..15 (row chunk of 128)
    int b = blockIdx.z;                              // 0..1
    const float* p = x + ((size_t)b * SEQ + (size_t)y * 128) * DM + c;
    float acc = 0.f;
#pragma unroll 8
    for (int r = 0; r < 128; ++r) acc += p[(size_t)r * DM];
    P[(b * 16 + y) * DM + c] = acc;
}

// ---- K1b: finish column sum: xsum[b][c] = sum_y P ----
__global__ __launch_bounds__(256)
void colsum_final(const float* __restrict__ P, float* __restrict__ xsum) {
    int c = blockIdx.x * blockDim.x + threadIdx.x;   // 0..2047
    int b = blockIdx.y;
    float a = 0.f;
#pragma unroll
    for (int y = 0; y < 16; ++y) a += P[(b * 16 + y) * DM + c];
    xsum[b * DM + c] = a;
}

// ---- K2: matvec o[b][n] = sum_k v[b][k] * W[n][k]  (W row-major [D][D]) ----
__global__ __launch_bounds__(256)
void matvec_nt(const float* __restrict__ v, const float* __restrict__ W,
               float* __restrict__ o) {
    int w    = threadIdx.x >> 6;         // wave id 0..3
    int lane = threadIdx.x & 63;
    int n = blockIdx.x * 4 + w;          // output row 0..2047
    int b = blockIdx.y;
    const float4* wr = (const float4*)(W + (size_t)n * DM);
    const float4* vr = (const float4*)(v + (size_t)b * DM);
    float acc = 0.f;
#pragma unroll
    for (int i = lane; i < DM / 4; i += 64) {
        float4 a = wr[i];
        float4 xx = vr[i];
        acc += a.x * xx.x + a.y * xx.y + a.z * xx.z + a.w * xx.w;
    }
#pragma unroll
    for (int m = 32; m; m >>= 1) acc += __shfl_xor(acc, m, 64);
    if (lane == 0) o[b * DM + n] = acc;
}

// ---- K3: broadcast r[b][:] into every q row of out[b][q][:] ----
__global__ __launch_bounds__(256)
void bcast_out(const float* __restrict__ r, float* __restrict__ out, int n4) {
    int i = blockIdx.x * blockDim.x + threadIdx.x;   // float4 index
    if (i >= n4) return;
    int b  = (i >= (SEQ * DM / 4)) ? 1 : 0;
    int j4 = i & (DM / 4 - 1);
    ((float4*)out)[i] = ((const float4*)r)[b * (DM / 4) + j4];
}

extern "C" void kernel_launch(void* const* d_in, const int* in_sizes, int n_in,
                              void* d_out, int out_size, void* d_ws, size_t ws_size,
                              hipStream_t stream) {
    const float* x  = (const float*)d_in[0];
    const float* wv = (const float*)d_in[3];
    const float* wo = (const float*)d_in[4];
    float* out = (float*)d_out;

    float* ws   = (float*)d_ws;
    float* P    = ws;                 // 32 * 2048 floats
    float* xsum = P + 32 * DM;        // 2 * 2048
    float* sv   = xsum + 2 * DM;      // 2 * 2048
    float* rr   = sv + 2 * DM;        // 2 * 2048

    colsum_part <<<dim3(DM / 256, 16, 2), 256, 0, stream>>>(x, P);
    colsum_final<<<dim3(DM / 256, 2),     256, 0, stream>>>(P, xsum);
    matvec_nt   <<<dim3(DM / 4, 2),       256, 0, stream>>>(xsum, wv, sv);
    matvec_nt   <<<dim3(DM / 4, 2),       256, 0, stream>>>(sv, wo, rr);

    int n4 = 2 * SEQ * DM / 4;
    bcast_out   <<<dim3(n4 / 256),        256, 0, stream>>>(rr, out, n4);
}